// Round 8
// baseline (163.562 us; speedup 1.0000x reference)
//
#include <hip/hip_runtime.h>
#include <math.h>

#define BATCH      128
#define N_ATOMS    4096
#define NB         4095
#define NA         4094
#define NT         4093
#define FSTRIDE    184185              // floats per sample (odd!)
#define TOTAL_F4   5893920u            // 128*184185/4 (exact)
#define EPSV       1e-8f
#define TILE_F     1080                // lcm-aligned: 40 bonds / 30 angles / 24 tors / 40 atoms
#define NTILES     171                 // ceil(184185/1080)
#define SCR_F4     272

// ---- d_ws layout (floats/records; all 16B-aligned) ----
#define PLANE      (BATCH * N_ATOMS)               // 524288 floats = 2 MB
#define WS_CX      0
#define WS_CY      PLANE
#define WS_CZ      (2 * PLANE)
#define WS_BND_B   ((size_t)3 * PLANE * 4)         // ushort4 [128][4096] = 4 MB
#define WS_ANG_B   (WS_BND_B + (size_t)BATCH * 4096 * 8)
#define WS_TOR_B   (WS_ANG_B + (size_t)BATCH * 4096 * 8)   // uint4 [128][4096] = 8 MB
#define WS_END_B   (WS_TOR_B + (size_t)BATCH * 4096 * 16)  // 22 MB

// Zero-cost compiler fence for the wave-private LDS scratch round-trip.
// Cross-lane store->read dep is invisible to per-thread alias analysis
// (R5 miscompiled without it). DS pipe runs a wave's LDS ops in order.
#define WAVE_LDS_FENCE()  do { asm volatile("" ::: "memory"); \
                               __builtin_amdgcn_wave_barrier(); } while (0)

// =================== K1: single-pass stream + compact extraction ===================
// 512 blocks x 512 threads (8 waves). Each block: one sample, 43-tile slice.
// No __syncthreads, no redundancy: every byte of F read exactly once chip-wide.
__global__ __launch_bounds__(512, 1) void
extract_kernel(const float* __restrict__ F, float* __restrict__ ws)
{
    __shared__ __align__(16) float4 scr[8][SCR_F4];   // 34 KB

    const int b   = blockIdx.x;
    const int x   = b & 7;             // XCD slot
    const int g   = b >> 3;            // 0..63
    const int s   = (g & 15) * 8 + x;  // sample 0..127, XCD-pinned
    const int p   = g >> 4;            // quarter 0..3
    const int tid = threadIdx.x;
    const int w   = tid >> 6;          // wave 0..7
    const int l   = tid & 63;
    const size_t sbase = (size_t)s * FSTRIDE;
    const int d = (int)(sbase & 3);
    const float4* __restrict__ F4 = (const float4*)F;

    float* __restrict__ cx = ws + WS_CX + (size_t)s * N_ATOMS;
    float* __restrict__ cy = ws + WS_CY + (size_t)s * N_ATOMS;
    float* __restrict__ cz = ws + WS_CZ + (size_t)s * N_ATOMS;
    ushort4* __restrict__ bw = (ushort4*)((char*)ws + WS_BND_B) + (size_t)s * 4096;
    ushort4* __restrict__ aw = (ushort4*)((char*)ws + WS_ANG_B) + (size_t)s * 4096;
    uint4*   __restrict__ tw = (uint4*)  ((char*)ws + WS_TOR_B) + (size_t)s * 4096;

    const int tlo = p * 43;
    const int thi = (tlo + 43 < NTILES) ? tlo + 43 : NTILES;
    float* const swf = (float*)scr[w];

    float4 cur[5];
    int t = tlo + w;
    if (t < thi) {
        const size_t q0 = (sbase + (size_t)t * TILE_F) >> 2;
        const int nf = (FSTRIDE - t * TILE_F < TILE_F) ? FSTRIDE - t * TILE_F : TILE_F;
        const int nq = (d + nf + 3) >> 2;
        #pragma unroll
        for (int i = 0; i < 5; ++i) {
            const int k = l + 64 * i;
            cur[i] = (k < nq && q0 + k < TOTAL_F4) ? F4[q0 + k]
                                                   : make_float4(0.f, 0.f, 0.f, 0.f);
        }
    }
    for (; t < thi; t += 8) {
        const int tn = t + 8;
        float4 nxt[5];
        #pragma unroll
        for (int i = 0; i < 5; ++i) nxt[i] = make_float4(0.f, 0.f, 0.f, 0.f);
        if (tn < thi) {
            const size_t q0 = (sbase + (size_t)tn * TILE_F) >> 2;
            const int nf = (FSTRIDE - tn * TILE_F < TILE_F) ? FSTRIDE - tn * TILE_F : TILE_F;
            const int nq = (d + nf + 3) >> 2;
            #pragma unroll
            for (int i = 0; i < 5; ++i) {
                const int k = l + 64 * i;
                if (k < nq && q0 + k < TOTAL_F4) nxt[i] = F4[q0 + k];
            }
        }
        #pragma unroll
        for (int i = 0; i < 4; ++i) scr[w][l + 64 * i] = cur[i];
        if (l < 15) scr[w][l + 256] = cur[4];
        WAVE_LDS_FENCE();                           // RAW: stores -> cross-lane reads

        // coords: rows 27i+{5,14,23}, 40 atoms/tile (tile 102: 16; tiles>=103: none)
        int nat = N_ATOMS - 40 * t; nat = (nat > 40) ? 40 : nat;
        if (l < nat) {
            const int base = d + 27 * l;
            const int a = 40 * t + l;
            cx[a] = swf[base + 5];
            cy[a] = swf[base + 14];
            cz[a] = swf[base + 23];
        }
        // bonds: 27i+{6,15,24}
        int nb = NB - 40 * t; nb = (nb > 40) ? 40 : nb;
        if (l < nb) {
            const int base = d + 27 * l;
            ushort4 r;
            r.x = (unsigned short)(int)swf[base + 6];
            r.y = (unsigned short)(int)swf[base + 15];
            r.z = (unsigned short)(int)swf[base + 24];
            r.w = 0;
            bw[40 * t + l] = r;
        }
        // angles: 36i+{7,16,25,34}
        int na = NA - 30 * t; na = (na > 30) ? 30 : na;
        if (l < na) {
            const int base = d + 36 * l;
            ushort4 r;
            r.x = (unsigned short)(int)swf[base + 7];
            r.y = (unsigned short)(int)swf[base + 16];
            r.z = (unsigned short)(int)swf[base + 25];
            r.w = (unsigned short)(int)swf[base + 34];
            aw[30 * t + l] = r;
        }
        // torsions: 45i+{8,17,26,35,44}
        int ntr = NT - 24 * t; ntr = (ntr > 24) ? 24 : ntr;
        if (l < ntr) {
            const int base = d + 45 * l;
            uint4 r;
            r.x = (unsigned)(unsigned short)(int)swf[base + 8]
                | ((unsigned)(unsigned short)(int)swf[base + 17] << 16);
            r.y = (unsigned)(unsigned short)(int)swf[base + 26]
                | ((unsigned)(unsigned short)(int)swf[base + 35] << 16);
            r.z = (unsigned)(unsigned short)(int)swf[base + 44];
            r.w = 0;
            tw[24 * t + l] = r;
        }
        WAVE_LDS_FENCE();                           // WAR: reads -> next iter stores
        #pragma unroll
        for (int i = 0; i < 5; ++i) cur[i] = nxt[i];
    }
}

// =================== K2: compact compute ===================
#define THREADS 1024
__global__ __launch_bounds__(THREADS, 1) void
energy_kernel(const float* __restrict__ ws,
              const float* __restrict__ bond_type,
              const float* __restrict__ angle_type,
              const float* __restrict__ tor_type,
              const int*   __restrict__ multiplicity,
              const float* __restrict__ opt_pars,
              float*       __restrict__ out)
{
    __shared__ float scx[N_ATOMS];
    __shared__ float scy[N_ATOMS];
    __shared__ float scz[N_ATOMS];
    __shared__ float sbt[30], sat[26], stt[50], smu[25];
    __shared__ float sred[16 * 3];

    const int b   = blockIdx.x;
    const int x   = b & 7;
    const int g   = b >> 3;            // 0..31
    const int s   = (g & 15) * 8 + x;  // same XCD slot as K1's writer for this sample
    const int p   = g >> 4;            // half 0..1
    const int tid = threadIdx.x;
    const int w   = tid >> 6;
    const int l   = tid & 63;

    if (tid < 30)                      sbt[tid]       = bond_type[tid];
    else if (tid >= 32 && tid < 58)    sat[tid - 32]  = angle_type[tid - 32];
    else if (tid >= 64 && tid < 114)   stt[tid - 64]  = tor_type[tid - 64];
    else if (tid >= 128 && tid < 153)  smu[tid - 128] = (float)multiplicity[tid - 128];

    // coalesced coord staging: exactly one float4 per thread per plane
    {
        const float4* __restrict__ cx4 = (const float4*)(ws + WS_CX + (size_t)s * N_ATOMS);
        const float4* __restrict__ cy4 = (const float4*)(ws + WS_CY + (size_t)s * N_ATOMS);
        const float4* __restrict__ cz4 = (const float4*)(ws + WS_CZ + (size_t)s * N_ATOMS);
        ((float4*)scx)[tid] = cx4[tid];
        ((float4*)scy)[tid] = cy4[tid];
        ((float4*)scz)[tid] = cz4[tid];
    }
    __syncthreads();

    float e_bond = 0.f, e_ang = 0.f, e_tor = 0.f;
    const int lo = p * 2048;

    // bonds
    {
        const ushort4* __restrict__ bp =
            (const ushort4*)((const char*)ws + WS_BND_B) + (size_t)s * 4096;
        const int hi = (lo + 2048 < NB) ? lo + 2048 : NB;
        for (int i = lo + tid; i < hi; i += THREADS) {
            const ushort4 u = bp[i];
            const int a0 = u.x, a1 = u.y, bt = u.z;
            const float dx = scx[a0] - scx[a1];
            const float dy = scy[a0] - scy[a1];
            const float dz = scz[a0] - scz[a1];
            const float r  = sqrtf(dx*dx + dy*dy + dz*dz + EPSV);
            const float t0 = r - sbt[bt * 2 + 1];
            e_bond += sbt[bt * 2 + 0] * t0 * t0;
        }
    }
    // angles
    {
        const ushort4* __restrict__ ap =
            (const ushort4*)((const char*)ws + WS_ANG_B) + (size_t)s * 4096;
        const int hi = (lo + 2048 < NA) ? lo + 2048 : NA;
        for (int i = lo + tid; i < hi; i += THREADS) {
            const ushort4 u = ap[i];
            const int a0 = u.x, a1 = u.y, a2 = u.z, at = u.w;
            const float v1x = scx[a0] - scx[a1];
            const float v1y = scy[a0] - scy[a1];
            const float v1z = scz[a0] - scz[a1];
            const float v2x = scx[a2] - scx[a1];
            const float v2y = scy[a2] - scy[a1];
            const float v2z = scz[a2] - scz[a1];
            const float d12 = v1x*v2x + v1y*v2y + v1z*v2z;
            const float n1  = sqrtf(v1x*v1x + v1y*v1y + v1z*v1z + EPSV);
            const float n2  = sqrtf(v2x*v2x + v2y*v2y + v2z*v2z + EPSV);
            float cosang = d12 / (n1 * n2);
            cosang = fminf(fmaxf(cosang, -1.0f + 1e-6f), 1.0f - 1e-6f);
            const float t0 = acosf(cosang) - sat[at * 2 + 1];
            e_ang += sat[at * 2 + 0] * t0 * t0;
        }
    }
    // torsions
    {
        const uint4* __restrict__ tp =
            (const uint4*)((const char*)ws + WS_TOR_B) + (size_t)s * 4096;
        const int hi = (lo + 2048 < NT) ? lo + 2048 : NT;
        for (int i = lo + tid; i < hi; i += THREADS) {
            const uint4 u = tp[i];
            const int ai = u.x & 0xFFFF, aj = u.x >> 16;
            const int ak = u.y & 0xFFFF, al = u.y >> 16;
            const int tt = u.z & 0xFFFF;
            const float b1x = scx[aj] - scx[ai], b1y = scy[aj] - scy[ai], b1z = scz[aj] - scz[ai];
            const float b2x = scx[ak] - scx[aj], b2y = scy[ak] - scy[aj], b2z = scz[ak] - scz[aj];
            const float b3x = scx[al] - scx[ak], b3y = scy[al] - scy[ak], b3z = scz[al] - scz[ak];
            const float n1x = b1y*b2z - b1z*b2y;
            const float n1y = b1z*b2x - b1x*b2z;
            const float n1z = b1x*b2y - b1y*b2x;
            const float n2x = b2y*b3z - b2z*b3y;
            const float n2y = b2z*b3x - b2x*b3z;
            const float n2z = b2x*b3y - b2y*b3x;
            const float inv = 1.0f / sqrtf(b2x*b2x + b2y*b2y + b2z*b2z + EPSV);
            const float bnx = b2x * inv, bny = b2y * inv, bnz = b2z * inv;
            const float m1x = n1y*bnz - n1z*bny;
            const float m1y = n1z*bnx - n1x*bnz;
            const float m1z = n1x*bny - n1y*bnx;
            const float phi = atan2f(m1x*n2x + m1y*n2y + m1z*n2z,
                                     n1x*n2x + n1y*n2y + n1z*n2z);
            e_tor += stt[tt * 2 + 0] * (1.0f + cosf(smu[tt] * phi - stt[tt * 2 + 1]));
        }
    }

    for (int off = 32; off > 0; off >>= 1) {
        e_bond += __shfl_down(e_bond, off);
        e_ang  += __shfl_down(e_ang,  off);
        e_tor  += __shfl_down(e_tor,  off);
    }
    if (l == 0) {
        sred[w * 3 + 0] = e_bond;
        sred[w * 3 + 1] = e_ang;
        sred[w * 3 + 2] = e_tor;
    }
    __syncthreads();
    if (tid == 0) {
        float eb = 0.f, ea = 0.f, et = 0.f;
        for (int i = 0; i < 16; ++i) {
            eb += sred[i * 3 + 0];
            ea += sred[i * 3 + 1];
            et += sred[i * 3 + 2];
        }
        atomicAdd(&out[s * 3 + 0], opt_pars[0] * eb);
        atomicAdd(&out[s * 3 + 1], opt_pars[1] * ea);
        atomicAdd(&out[s * 3 + 2], opt_pars[2] * et);
    }
}

extern "C" void kernel_launch(void* const* d_in, const int* in_sizes, int n_in,
                              void* d_out, int out_size, void* d_ws, size_t ws_size,
                              hipStream_t stream) {
    const float* F            = (const float*)d_in[0];
    // d_in[1] = lengths (constant, unused)
    const float* bond_type    = (const float*)d_in[2];
    const float* angle_type   = (const float*)d_in[3];
    const float* tor_type     = (const float*)d_in[4];
    const int*   multiplicity = (const int*)  d_in[5];
    const float* opt_pars     = (const float*)d_in[6];
    float* out = (float*)d_out;
    float* ws  = (float*)d_ws;

    hipMemsetAsync(out, 0, (size_t)out_size * sizeof(float), stream);

    extract_kernel<<<dim3(512), dim3(512), 0, stream>>>(F, ws);
    energy_kernel<<<dim3(256), dim3(THREADS), 0, stream>>>(
        ws, bond_type, angle_type, tor_type, multiplicity, opt_pars, out);
}